// Round 5
// baseline (194.455 us; speedup 1.0000x reference)
//
#include <hip/hip_runtime.h>

// ---------------------------------------------------------------------------
// PlaneEmbeddingNetwork, round 5.
// R4 post-mortem: VALU-issue bound; measured ~2645 VALU issues/thread vs
// ~1500 of real math. Gap = __shfl recomputing bpermute addresses per call
// (~5 VALU x 160 shuffles), scalar fco tail, softmax max machinery.
// This round (structure unchanged from R4: 4 lanes/face, no LDS arrays,
// no barriers):
//  1. Hoist the 5 bpermute byte-addresses (quad-rot r=1..3, xor1, xor2);
//     call __builtin_amdgcn_ds_bpermute directly.
//  2. v2f (v_pk_fma_f32) fco accumulate: 4 pk/channel vs 8 scalar fma.
//  3. Softmax without max-subtract (|score*scale| <~ 20 << 127 exp2 range),
//     scale*log2e folded into a single exp2 per score.
// ---------------------------------------------------------------------------

typedef float v2f __attribute__((ext_vector_type(2)));

static __device__ __forceinline__ v2f splat2(float x) { v2f r; r.x = x; r.y = x; return r; }
static __device__ __forceinline__ v2f fma2(v2f a, v2f b, v2f c) {
    return __builtin_elementwise_fma(a, b, c);
}
static __device__ __forceinline__ float bperm(int addr, float x) {
    return __builtin_bit_cast(float,
        __builtin_amdgcn_ds_bpermute(addr, __builtin_bit_cast(int, x)));
}
static __device__ __forceinline__ v2f bperm2(int addr, v2f x) {
    v2f r; r.x = bperm(addr, x.x); r.y = bperm(addr, x.y); return r;
}

// Setup: W1T[c][d] = sum_e w_out[d*16+e] * fc_w[e*32+c]   -> ws[c*16+d]
//        b1[c]     = sum_e b_out[e] * fc_w[e*32+c] + fc_b[c] -> ws[512+c]
__global__ void fold_w1(const float* __restrict__ w_out,
                        const float* __restrict__ b_out,
                        const float* __restrict__ fc_w,
                        const float* __restrict__ fc_b,
                        float* __restrict__ ws) {
    int tid = threadIdx.x;
    if (tid < 512) {
        int c = tid >> 4, d = tid & 15;
        float acc = 0.f;
#pragma unroll
        for (int e = 0; e < 16; ++e)
            acc = fmaf(w_out[d * 16 + e], fc_w[e * 32 + c], acc);
        ws[c * 16 + d] = acc;
    } else if (tid < 544) {
        int c = tid - 512;
        float acc = fc_b[c];
#pragma unroll
        for (int e = 0; e < 16; ++e)
            acc = fmaf(b_out[e], fc_w[e * 32 + c], acc);
        ws[512 + c] = acc;
    }
}

__launch_bounds__(256, 3)
__global__ void face_net(const float* __restrict__ node,
                         const int*   __restrict__ fids,
                         const float* __restrict__ w_in,
                         const float* __restrict__ b_in,
                         const float* __restrict__ w1b1,   // ws: W1T[32][16], b1[32]
                         const float* __restrict__ fco_w,
                         const float* __restrict__ fco_b,
                         float* __restrict__ out, int F) {
    const int g = blockIdx.x * 256 + threadIdx.x;
    const int f = g >> 2;
    if (f >= F) return;               // whole quads exit together (face-aligned)
    const int t = g & 3;

    // ---- hoisted bpermute byte-addresses (computed once) ----
    const int lane  = threadIdx.x & 63;
    const int qbase = (lane & ~3) << 2;
    const int ar1 = qbase | (((lane + 1) & 3) << 2);   // quad-rot +1
    const int ar2 = qbase | (((lane + 2) & 3) << 2);   // quad-rot +2
    const int ar3 = qbase | (((lane + 3) & 3) << 2);   // quad-rot +3
    const int ax1 = (lane ^ 1) << 2;                   // xor 1
    const int ax2 = (lane ^ 2) << 2;                   // xor 2

    // ---- gather own token's embedding (coalesced id load; 64B row fetch)
    const int nid = fids[g];
    const float* xp = node + (size_t)nid * 16;
    const float4 xv0 = *reinterpret_cast<const float4*>(xp);
    const float4 xv1 = *reinterpret_cast<const float4*>(xp + 4);
    const float4 xv2 = *reinterpret_cast<const float4*>(xp + 8);
    const float4 xv3 = *reinterpret_cast<const float4*>(xp + 12);
    const float xa[16] = {xv0.x, xv0.y, xv0.z, xv0.w, xv1.x, xv1.y, xv1.z, xv1.w,
                          xv2.x, xv2.y, xv2.z, xv2.w, xv3.x, xv3.y, xv3.z, xv3.w};

    // ---- qkv projection for OWN token (packed). k-bias dropped (softmax
    //      row-constant: score[t][j] = q_t.k_j + q_t.bk, const over j).
    const v2f* b2 = reinterpret_cast<const v2f*>(b_in);
    v2f q[8], k[8], v[8];
#pragma unroll
    for (int o = 0; o < 8; ++o) { q[o] = b2[o]; k[o] = splat2(0.f); v[o] = b2[16 + o]; }
#pragma unroll
    for (int d = 0; d < 16; ++d) {
        const v2f* wr = reinterpret_cast<const v2f*>(w_in + d * 48);  // uniform s_load
        const v2f xs = splat2(xa[d]);
#pragma unroll
        for (int o = 0; o < 8; ++o) {
            q[o] = fma2(xs, wr[o],      q[o]);
            k[o] = fma2(xs, wr[8 + o],  k[o]);
            v[o] = fma2(xs, wr[16 + o], v[o]);
        }
    }

    // ---- scores: p{h}[r] = q_t . k_{(t+r)%4}, k gathered via hoisted-addr
    //      bpermute from the ORIGINAL k. Softmax over r covers all j; PV
    //      uses the identical r->j bijection, so this is exact.
    float p0[4], p1[4];
    const int arr[3] = {ar1, ar2, ar3};
    {   // r = 0: self, no shuffle
        v2f a0 = q[0] * k[0];
        v2f a1 = q[4] * k[4];
#pragma unroll
        for (int d = 1; d < 4; ++d) {
            a0 = fma2(q[d], k[d], a0);
            a1 = fma2(q[4 + d], k[4 + d], a1);
        }
        p0[0] = a0.x + a0.y;
        p1[0] = a1.x + a1.y;
    }
#pragma unroll
    for (int r = 1; r < 4; ++r) {
        const int ad = arr[r - 1];
        v2f kr[8];
#pragma unroll
        for (int d = 0; d < 8; ++d) kr[d] = bperm2(ad, k[d]);
        v2f a0 = q[0] * kr[0];
        v2f a1 = q[4] * kr[4];
#pragma unroll
        for (int d = 1; d < 4; ++d) {
            a0 = fma2(q[d], kr[d], a0);
            a1 = fma2(q[4 + d], kr[4 + d], a1);
        }
        p0[r] = a0.x + a0.y;
        p1[r] = a1.x + a1.y;
    }
    {   // softmax, no max-subtract: raw score * scale bounded (|.|<~20),
        // exp2 range +-127. C = (1/sqrt(8)) * log2(e).
        const float C = 0.51006974841f;
        float s0 = 0.f, s1 = 0.f;
#pragma unroll
        for (int j = 0; j < 4; ++j) {
            p0[j] = __builtin_amdgcn_exp2f(p0[j] * C); s0 += p0[j];
            p1[j] = __builtin_amdgcn_exp2f(p1[j] * C); s1 += p1[j];
        }
        const float r0 = __builtin_amdgcn_rcpf(s0);
        const float r1 = __builtin_amdgcn_rcpf(s1);
#pragma unroll
        for (int j = 0; j < 4; ++j) { p0[j] *= r0; p1[j] *= r1; }
    }

    // ---- PV: o_t = sum_r p[r] * v_{(t+r)%4}, v gathered from original regs
    v2f o[8];
#pragma unroll
    for (int d = 0; d < 4; ++d) {
        o[d]     = splat2(p0[0]) * v[d];
        o[4 + d] = splat2(p1[0]) * v[4 + d];
    }
#pragma unroll
    for (int r = 1; r < 4; ++r) {
        const int ad = arr[r - 1];
        const v2f ps0 = splat2(p0[r]), ps1 = splat2(p1[r]);
#pragma unroll
        for (int d = 0; d < 8; ++d) {
            const v2f vr = bperm2(ad, v[d]);
            if (d < 4) o[d] = fma2(ps0, vr, o[d]);
            else       o[d] = fma2(ps1, vr, o[d]);
        }
    }

    // ---- fused: h_t[c] = relu(o_t . W1T[c] + b1[c]); pooled_c = quadsum/4;
    //      each lane accumulates its own 8 output columns [t*8, t*8+8).
    const int t8 = t * 8;
    const float4 ob0 = *reinterpret_cast<const float4*>(fco_b + t8);
    const float4 ob1 = *reinterpret_cast<const float4*>(fco_b + t8 + 4);
    v2f oacc[4];
    oacc[0].x = ob0.x; oacc[0].y = ob0.y; oacc[1].x = ob0.z; oacc[1].y = ob0.w;
    oacc[2].x = ob1.x; oacc[2].y = ob1.y; oacc[3].x = ob1.z; oacc[3].y = ob1.w;
    const float* fwt = fco_w + t8;   // lane-varying base, hoisted

#pragma unroll 4
    for (int c = 0; c < 32; ++c) {
        const v2f* w1r = reinterpret_cast<const v2f*>(w1b1 + c * 16);  // uniform
        v2f a = o[0] * w1r[0];
#pragma unroll
        for (int d = 1; d < 8; ++d) a = fma2(o[d], w1r[d], a);
        const float h = fmaxf(a.x + a.y + w1b1[512 + c], 0.f);
        float s = h + bperm(ax1, h);
        s = s + bperm(ax2, s);
        const float pc = s * 0.25f;
        const v2f ps = splat2(pc);
        // lane-varying columns of fco_w: 4KB table, L1-resident
        const float4 f0 = *reinterpret_cast<const float4*>(fwt + c * 32);
        const float4 f1 = *reinterpret_cast<const float4*>(fwt + c * 32 + 4);
        v2f w01; w01.x = f0.x; w01.y = f0.y;
        v2f w23; w23.x = f0.z; w23.y = f0.w;
        v2f w45; w45.x = f1.x; w45.y = f1.y;
        v2f w67; w67.x = f1.z; w67.y = f1.w;
        oacc[0] = fma2(ps, w01, oacc[0]);
        oacc[1] = fma2(ps, w23, oacc[1]);
        oacc[2] = fma2(ps, w45, oacc[2]);
        oacc[3] = fma2(ps, w67, oacc[3]);
    }

    // ---- store: 16B/lane, contiguous across the quad and wave
    float* op = out + (size_t)f * 32 + t8;
    *reinterpret_cast<float4*>(op)     = make_float4(oacc[0].x, oacc[0].y, oacc[1].x, oacc[1].y);
    *reinterpret_cast<float4*>(op + 4) = make_float4(oacc[2].x, oacc[2].y, oacc[3].x, oacc[3].y);
}

extern "C" void kernel_launch(void* const* d_in, const int* in_sizes, int n_in,
                              void* d_out, int out_size, void* d_ws, size_t ws_size,
                              hipStream_t stream) {
    const float* node  = (const float*)d_in[0];
    const int*   fids  = (const int*)  d_in[1];
    const float* w_in  = (const float*)d_in[2];
    const float* b_in  = (const float*)d_in[3];
    const float* w_out = (const float*)d_in[4];
    const float* b_out = (const float*)d_in[5];
    const float* fc_w  = (const float*)d_in[6];
    const float* fc_b  = (const float*)d_in[7];
    const float* fco_w = (const float*)d_in[8];
    const float* fco_b = (const float*)d_in[9];
    float* out = (float*)d_out;
    float* ws  = (float*)d_ws;
    const int F = in_sizes[1] / 4;

    hipLaunchKernelGGL(fold_w1, dim3(1), dim3(576), 0, stream,
                       w_out, b_out, fc_w, fc_b, ws);
    const int threads = F * 4;
    const int blocks = (threads + 255) / 256;
    hipLaunchKernelGGL(face_net, dim3(blocks), dim3(256), 0, stream,
                       node, fids, w_in, b_in, ws, fco_w, fco_b, out, F);
}

// Round 6
// 193.167 us; speedup vs baseline: 1.0067x; 1.0067x over previous
//
#include <hip/hip_runtime.h>

// ---------------------------------------------------------------------------
// PlaneEmbeddingNetwork, round 6.
// R5 post-mortem: instr-count shaves were no-ops (compiler already hoisted);
// wall is SERIALIZED LDS latency - the c-loop's per-channel quadsum did
// 2 dependent ds_bpermute round-trips x 32 channels (~1900 cyc/thread).
// This round, single change vs R5: BATCHED quad-reduction.
//   1. Compute all 32 h values into 16 v2f regs (no cross-lane).
//   2. Quad-reduce ALL channels in 2 bulk stages: 32 independent bpermutes
//      -> wait -> 16 pk-adds, x2 (xor1 then xor2). Two latency windows
//      instead of 64.
//   3. fco accumulate: pure register loop, 64 independent L1 float4 loads.
// Rest identical to R5 (4 lanes/face, bperm rotations for scores/PV).
// ---------------------------------------------------------------------------

typedef float v2f __attribute__((ext_vector_type(2)));

static __device__ __forceinline__ v2f splat2(float x) { v2f r; r.x = x; r.y = x; return r; }
static __device__ __forceinline__ v2f fma2(v2f a, v2f b, v2f c) {
    return __builtin_elementwise_fma(a, b, c);
}
static __device__ __forceinline__ float bperm(int addr, float x) {
    return __builtin_bit_cast(float,
        __builtin_amdgcn_ds_bpermute(addr, __builtin_bit_cast(int, x)));
}
static __device__ __forceinline__ v2f bperm2(int addr, v2f x) {
    v2f r; r.x = bperm(addr, x.x); r.y = bperm(addr, x.y); return r;
}

// Setup: W1T[c][d] = sum_e w_out[d*16+e] * fc_w[e*32+c]   -> ws[c*16+d]
//        b1[c]     = sum_e b_out[e] * fc_w[e*32+c] + fc_b[c] -> ws[512+c]
__global__ void fold_w1(const float* __restrict__ w_out,
                        const float* __restrict__ b_out,
                        const float* __restrict__ fc_w,
                        const float* __restrict__ fc_b,
                        float* __restrict__ ws) {
    int tid = threadIdx.x;
    if (tid < 512) {
        int c = tid >> 4, d = tid & 15;
        float acc = 0.f;
#pragma unroll
        for (int e = 0; e < 16; ++e)
            acc = fmaf(w_out[d * 16 + e], fc_w[e * 32 + c], acc);
        ws[c * 16 + d] = acc;
    } else if (tid < 544) {
        int c = tid - 512;
        float acc = fc_b[c];
#pragma unroll
        for (int e = 0; e < 16; ++e)
            acc = fmaf(b_out[e], fc_w[e * 32 + c], acc);
        ws[512 + c] = acc;
    }
}

__launch_bounds__(256, 3)
__global__ void face_net(const float* __restrict__ node,
                         const int*   __restrict__ fids,
                         const float* __restrict__ w_in,
                         const float* __restrict__ b_in,
                         const float* __restrict__ w1b1,   // ws: W1T[32][16], b1[32]
                         const float* __restrict__ fco_w,
                         const float* __restrict__ fco_b,
                         float* __restrict__ out, int F) {
    const int g = blockIdx.x * 256 + threadIdx.x;
    const int f = g >> 2;
    if (f >= F) return;               // whole quads exit together (face-aligned)
    const int t = g & 3;

    // ---- hoisted bpermute byte-addresses ----
    const int lane  = threadIdx.x & 63;
    const int qbase = (lane & ~3) << 2;
    const int ar1 = qbase | (((lane + 1) & 3) << 2);   // quad-rot +1
    const int ar2 = qbase | (((lane + 2) & 3) << 2);   // quad-rot +2
    const int ar3 = qbase | (((lane + 3) & 3) << 2);   // quad-rot +3
    const int ax1 = (lane ^ 1) << 2;                   // xor 1
    const int ax2 = (lane ^ 2) << 2;                   // xor 2

    // ---- gather own token's embedding (coalesced id load; 64B row fetch)
    const int nid = fids[g];
    const float* xp = node + (size_t)nid * 16;
    const float4 xv0 = *reinterpret_cast<const float4*>(xp);
    const float4 xv1 = *reinterpret_cast<const float4*>(xp + 4);
    const float4 xv2 = *reinterpret_cast<const float4*>(xp + 8);
    const float4 xv3 = *reinterpret_cast<const float4*>(xp + 12);
    const float xa[16] = {xv0.x, xv0.y, xv0.z, xv0.w, xv1.x, xv1.y, xv1.z, xv1.w,
                          xv2.x, xv2.y, xv2.z, xv2.w, xv3.x, xv3.y, xv3.z, xv3.w};

    // ---- qkv projection for OWN token (packed). k-bias dropped.
    const v2f* b2 = reinterpret_cast<const v2f*>(b_in);
    v2f q[8], k[8], v[8];
#pragma unroll
    for (int o = 0; o < 8; ++o) { q[o] = b2[o]; k[o] = splat2(0.f); v[o] = b2[16 + o]; }
#pragma unroll
    for (int d = 0; d < 16; ++d) {
        const v2f* wr = reinterpret_cast<const v2f*>(w_in + d * 48);  // uniform s_load
        const v2f xs = splat2(xa[d]);
#pragma unroll
        for (int o = 0; o < 8; ++o) {
            q[o] = fma2(xs, wr[o],      q[o]);
            k[o] = fma2(xs, wr[8 + o],  k[o]);
            v[o] = fma2(xs, wr[16 + o], v[o]);
        }
    }

    // ---- scores: p{h}[r] = q_t . k_{(t+r)%4} via bulk bpermute rotations
    float p0[4], p1[4];
    const int arr[3] = {ar1, ar2, ar3};
    {
        v2f a0 = q[0] * k[0];
        v2f a1 = q[4] * k[4];
#pragma unroll
        for (int d = 1; d < 4; ++d) {
            a0 = fma2(q[d], k[d], a0);
            a1 = fma2(q[4 + d], k[4 + d], a1);
        }
        p0[0] = a0.x + a0.y;
        p1[0] = a1.x + a1.y;
    }
#pragma unroll
    for (int r = 1; r < 4; ++r) {
        const int ad = arr[r - 1];
        v2f kr[8];
#pragma unroll
        for (int d = 0; d < 8; ++d) kr[d] = bperm2(ad, k[d]);
        v2f a0 = q[0] * kr[0];
        v2f a1 = q[4] * kr[4];
#pragma unroll
        for (int d = 1; d < 4; ++d) {
            a0 = fma2(q[d], kr[d], a0);
            a1 = fma2(q[4 + d], kr[4 + d], a1);
        }
        p0[r] = a0.x + a0.y;
        p1[r] = a1.x + a1.y;
    }
    {   // softmax, no max-subtract (|score*scale| <~ 20 << exp2 range)
        const float C = 0.51006974841f;   // (1/sqrt(8)) * log2(e)
        float s0 = 0.f, s1 = 0.f;
#pragma unroll
        for (int j = 0; j < 4; ++j) {
            p0[j] = __builtin_amdgcn_exp2f(p0[j] * C); s0 += p0[j];
            p1[j] = __builtin_amdgcn_exp2f(p1[j] * C); s1 += p1[j];
        }
        const float r0 = __builtin_amdgcn_rcpf(s0);
        const float r1 = __builtin_amdgcn_rcpf(s1);
#pragma unroll
        for (int j = 0; j < 4; ++j) { p0[j] *= r0; p1[j] *= r1; }
    }

    // ---- PV: o_t = sum_r p[r] * v_{(t+r)%4}
    v2f o[8];
#pragma unroll
    for (int d = 0; d < 4; ++d) {
        o[d]     = splat2(p0[0]) * v[d];
        o[4 + d] = splat2(p1[0]) * v[4 + d];
    }
#pragma unroll
    for (int r = 1; r < 4; ++r) {
        const int ad = arr[r - 1];
        const v2f ps0 = splat2(p0[r]), ps1 = splat2(p1[r]);
#pragma unroll
        for (int d = 0; d < 8; ++d) {
            const v2f vr = bperm2(ad, v[d]);
            if (d < 4) o[d] = fma2(ps0, vr, o[d]);
            else       o[d] = fma2(ps1, vr, o[d]);
        }
    }

    // ---- ALL 32 h values first (register-only): hv[i] = (h_{2i}, h_{2i+1})
    const v2f* b1v = reinterpret_cast<const v2f*>(w1b1 + 512);
    v2f hv[16];
#pragma unroll
    for (int cp = 0; cp < 16; ++cp) {
        const v2f* w0 = reinterpret_cast<const v2f*>(w1b1 + (2 * cp) * 16);      // uniform
        const v2f* w1 = reinterpret_cast<const v2f*>(w1b1 + (2 * cp + 1) * 16);  // uniform
        v2f a0 = o[0] * w0[0];
        v2f a1 = o[0] * w1[0];
#pragma unroll
        for (int d = 1; d < 8; ++d) {
            a0 = fma2(o[d], w0[d], a0);
            a1 = fma2(o[d], w1[d], a1);
        }
        v2f h;
        h.x = a0.x + a0.y;
        h.y = a1.x + a1.y;
        h = h + b1v[cp];
        hv[cp] = __builtin_elementwise_max(h, splat2(0.f));
    }

    // ---- BULK quad-reduction: 2 latency windows of 32 independent bpermutes
#pragma unroll
    for (int cp = 0; cp < 16; ++cp) hv[cp] = hv[cp] + bperm2(ax1, hv[cp]);
#pragma unroll
    for (int cp = 0; cp < 16; ++cp) hv[cp] = hv[cp] + bperm2(ax2, hv[cp]);
    // hv[cp] now holds (pooled_{2cp}, pooled_{2cp+1}) * 4 in every lane

    // ---- fco accumulate: each lane owns output columns [t*8, t*8+8)
    const int t8 = t * 8;
    const float4 ob0 = *reinterpret_cast<const float4*>(fco_b + t8);
    const float4 ob1 = *reinterpret_cast<const float4*>(fco_b + t8 + 4);
    v2f oacc[4];
    oacc[0].x = ob0.x; oacc[0].y = ob0.y; oacc[1].x = ob0.z; oacc[1].y = ob0.w;
    oacc[2].x = ob1.x; oacc[2].y = ob1.y; oacc[3].x = ob1.z; oacc[3].y = ob1.w;
    const float* fwt = fco_w + t8;   // lane-varying base

#pragma unroll 8
    for (int c = 0; c < 32; ++c) {
        const float pc = ((c & 1) ? hv[c >> 1].y : hv[c >> 1].x) * 0.25f;
        const v2f ps = splat2(pc);
        const float4 f0 = *reinterpret_cast<const float4*>(fwt + c * 32);      // L1
        const float4 f1 = *reinterpret_cast<const float4*>(fwt + c * 32 + 4);  // L1
        v2f w01; w01.x = f0.x; w01.y = f0.y;
        v2f w23; w23.x = f0.z; w23.y = f0.w;
        v2f w45; w45.x = f1.x; w45.y = f1.y;
        v2f w67; w67.x = f1.z; w67.y = f1.w;
        oacc[0] = fma2(ps, w01, oacc[0]);
        oacc[1] = fma2(ps, w23, oacc[1]);
        oacc[2] = fma2(ps, w45, oacc[2]);
        oacc[3] = fma2(ps, w67, oacc[3]);
    }

    // ---- store: 16B/lane, contiguous across the quad and wave
    float* op = out + (size_t)f * 32 + t8;
    *reinterpret_cast<float4*>(op)     = make_float4(oacc[0].x, oacc[0].y, oacc[1].x, oacc[1].y);
    *reinterpret_cast<float4*>(op + 4) = make_float4(oacc[2].x, oacc[2].y, oacc[3].x, oacc[3].y);
}

extern "C" void kernel_launch(void* const* d_in, const int* in_sizes, int n_in,
                              void* d_out, int out_size, void* d_ws, size_t ws_size,
                              hipStream_t stream) {
    const float* node  = (const float*)d_in[0];
    const int*   fids  = (const int*)  d_in[1];
    const float* w_in  = (const float*)d_in[2];
    const float* b_in  = (const float*)d_in[3];
    const float* w_out = (const float*)d_in[4];
    const float* b_out = (const float*)d_in[5];
    const float* fc_w  = (const float*)d_in[6];
    const float* fc_b  = (const float*)d_in[7];
    const float* fco_w = (const float*)d_in[8];
    const float* fco_b = (const float*)d_in[9];
    float* out = (float*)d_out;
    float* ws  = (float*)d_ws;
    const int F = in_sizes[1] / 4;

    hipLaunchKernelGGL(fold_w1, dim3(1), dim3(576), 0, stream,
                       w_out, b_out, fc_w, fc_b, ws);
    const int threads = F * 4;
    const int blocks = (threads + 255) / 256;
    hipLaunchKernelGGL(face_net, dim3(blocks), dim3(256), 0, stream,
                       node, fids, w_in, b_in, ws, fco_w, fco_b, out, F);
}

// Round 7
// 171.286 us; speedup vs baseline: 1.1353x; 1.1277x over previous
//
#include <hip/hip_runtime.h>
#include <stdint.h>

// ---------------------------------------------------------------------------
// PlaneEmbeddingNetwork, round 7.
// R4-R6 establish: VALU exec work stable ~5200 cyc/wave = 66us floor of the
// ~113us duration; occupancy/scheduling changes are neutral. fp32 scalar FMA
// (1 MAC/lane/cyc) is the 157TF ceiling; no packed-fp32 2x path on gfx950.
// This round: move dot-shaped MAC blocks to v_dot2_f32_f16 (2 f16 MACs/lane/
// cyc, f32 accumulate):
//   - qkv projection: 768 MACs 1536->768 cyc (weights pre-cvt to half2 in ws)
//   - h-loop (o @ W1T): 512 MACs 1024->512 cyc
//   - scores: q,k as half2; k bpermutes halve (48->24 DS ops)
// PV + fco stay f32 (accumulator structure / precision). Only INPUTS are
// f16-rounded (rel ~5e-4), accum stays f32 -> absmax ~3-6e-3 vs 1.23e-2.
// Structure otherwise identical to R5 (4 lanes/face, bperm quad rotations).
// ---------------------------------------------------------------------------

typedef float v2f __attribute__((ext_vector_type(2)));
typedef _Float16 v2h __attribute__((ext_vector_type(2)));

static __device__ __forceinline__ v2f splat2(float x) { v2f r; r.x = x; r.y = x; return r; }
static __device__ __forceinline__ v2f fma2(v2f a, v2f b, v2f c) {
    return __builtin_elementwise_fma(a, b, c);
}
static __device__ __forceinline__ float bperm(int addr, float x) {
    return __builtin_bit_cast(float,
        __builtin_amdgcn_ds_bpermute(addr, __builtin_bit_cast(int, x)));
}
static __device__ __forceinline__ v2f bperm2(int addr, v2f x) {
    v2f r; r.x = bperm(addr, x.x); r.y = bperm(addr, x.y); return r;
}
static __device__ __forceinline__ v2h bpermh(int addr, v2h x) {
    return __builtin_bit_cast(v2h,
        __builtin_amdgcn_ds_bpermute(addr, __builtin_bit_cast(int, x)));
}
static __device__ __forceinline__ v2h pkh(float a, float b) {
    v2h r; r.x = (_Float16)a; r.y = (_Float16)b; return r;  // RNE casts
}
static __device__ __forceinline__ float fdot2(v2h a, v2h b, float c) {
#if __has_builtin(__builtin_amdgcn_fdot2)
    return __builtin_amdgcn_fdot2(a, b, c, false);
#else
    return fmaf((float)a.x, (float)b.x, fmaf((float)a.y, (float)b.y, c));
#endif
}
static __device__ __forceinline__ v2h ldh2(const uint32_t* p) {
    return __builtin_bit_cast(v2h, *p);
}

// ---------------------------------------------------------------------------
// Setup kernel. ws layout (4-byte units):
//  [0   .. 384): half2 wqkv[o*8+p]  = (w_in[2p][o], w_in[2p+1][o]), o in [0,48)
//  [384 .. 640): half2 w1t[c*8+p]   = (W1T[c][2p], W1T[c][2p+1]),   c in [0,32)
//                where W1T[c][d] = sum_e w_out[d*16+e] * fc_w[e*32+c]
//  [640 .. 672): float b1[c] = sum_e b_out[e]*fc_w[e*32+c] + fc_b[c]
// ---------------------------------------------------------------------------
__global__ void fold_w(const float* __restrict__ w_in,
                       const float* __restrict__ w_out,
                       const float* __restrict__ b_out,
                       const float* __restrict__ fc_w,
                       const float* __restrict__ fc_b,
                       uint32_t* __restrict__ wsu) {
    const int tid = threadIdx.x;
    if (tid < 384) {                       // region A: packed w_in
        const int o = tid >> 3, p = tid & 7;
        const v2h h = pkh(w_in[(2 * p) * 48 + o], w_in[(2 * p + 1) * 48 + o]);
        wsu[tid] = __builtin_bit_cast(uint32_t, h);
    } else if (tid < 640) {                // region B: packed W1T
        const int i = tid - 384, c = i >> 3, p = i & 7;
        float a0 = 0.f, a1 = 0.f;
#pragma unroll
        for (int e = 0; e < 16; ++e) {
            a0 = fmaf(w_out[(2 * p) * 16 + e],     fc_w[e * 32 + c], a0);
            a1 = fmaf(w_out[(2 * p + 1) * 16 + e], fc_w[e * 32 + c], a1);
        }
        wsu[tid] = __builtin_bit_cast(uint32_t, pkh(a0, a1));
    } else if (tid < 672) {                // region C: b1 (f32)
        const int c = tid - 640;
        float acc = fc_b[c];
#pragma unroll
        for (int e = 0; e < 16; ++e)
            acc = fmaf(b_out[e], fc_w[e * 32 + c], acc);
        reinterpret_cast<float*>(wsu)[640 + c] = acc;
    }
}

__launch_bounds__(256, 3)
__global__ void face_net(const float* __restrict__ node,
                         const int*   __restrict__ fids,
                         const float* __restrict__ b_in,
                         const uint32_t* __restrict__ wsu,
                         const float* __restrict__ fco_w,
                         const float* __restrict__ fco_b,
                         float* __restrict__ out, int F) {
    const int g = blockIdx.x * 256 + threadIdx.x;
    const int f = g >> 2;
    if (f >= F) return;               // whole quads exit together (face-aligned)
    const int t = g & 3;

    // ---- hoisted bpermute byte-addresses ----
    const int lane  = threadIdx.x & 63;
    const int qbase = (lane & ~3) << 2;
    const int ar1 = qbase | (((lane + 1) & 3) << 2);   // quad-rot +1
    const int ar2 = qbase | (((lane + 2) & 3) << 2);   // quad-rot +2
    const int ar3 = qbase | (((lane + 3) & 3) << 2);   // quad-rot +3
    const int ax1 = (lane ^ 1) << 2;                   // xor 1
    const int ax2 = (lane ^ 2) << 2;                   // xor 2
    const int arr[3] = {ar1, ar2, ar3};

    // ---- gather own token's embedding; convert to 8 half2 d-pairs
    const int nid = fids[g];
    const float* xp = node + (size_t)nid * 16;
    const float4 xv0 = *reinterpret_cast<const float4*>(xp);
    const float4 xv1 = *reinterpret_cast<const float4*>(xp + 4);
    const float4 xv2 = *reinterpret_cast<const float4*>(xp + 8);
    const float4 xv3 = *reinterpret_cast<const float4*>(xp + 12);
    v2h xh[8];
    xh[0] = pkh(xv0.x, xv0.y); xh[1] = pkh(xv0.z, xv0.w);
    xh[2] = pkh(xv1.x, xv1.y); xh[3] = pkh(xv1.z, xv1.w);
    xh[4] = pkh(xv2.x, xv2.y); xh[5] = pkh(xv2.z, xv2.w);
    xh[6] = pkh(xv3.x, xv3.y); xh[7] = pkh(xv3.z, xv3.w);

    // ---- qkv projection via fdot2 (f32 accumulators, f16 inputs).
    //      k-bias dropped (softmax row-constant).
    float qa[16], ka[16], va[16];
#pragma unroll
    for (int o = 0; o < 16; ++o) {
        float aq = b_in[o], ak = 0.f, av = b_in[32 + o];
        const uint32_t* wq = wsu + o * 8;          // uniform -> s_load
        const uint32_t* wk = wsu + (16 + o) * 8;
        const uint32_t* wv = wsu + (32 + o) * 8;
#pragma unroll
        for (int p = 0; p < 8; ++p) {
            aq = fdot2(xh[p], ldh2(wq + p), aq);
            ak = fdot2(xh[p], ldh2(wk + p), ak);
            av = fdot2(xh[p], ldh2(wv + p), av);
        }
        qa[o] = aq; ka[o] = ak; va[o] = av;
    }

    // q,k as half2 pairs (halves k-bpermute count); v stays f32 for PV.
    v2h qh[8], kh[8];
    v2f v[8];
#pragma unroll
    for (int i = 0; i < 8; ++i) {
        qh[i] = pkh(qa[2 * i], qa[2 * i + 1]);
        kh[i] = pkh(ka[2 * i], ka[2 * i + 1]);
        v[i].x = va[2 * i]; v[i].y = va[2 * i + 1];
    }

    // ---- scores: p{h}[r] = q_t . k_{(t+r)%4} via fdot2; k rotated by bperm
    //      (8 DS ops/rotation). Head0 = pairs 0..3, head1 = pairs 4..7.
    float p0[4], p1[4];
    {
        float a0 = 0.f, a1 = 0.f;
#pragma unroll
        for (int d = 0; d < 4; ++d) {
            a0 = fdot2(qh[d], kh[d], a0);
            a1 = fdot2(qh[4 + d], kh[4 + d], a1);
        }
        p0[0] = a0; p1[0] = a1;
    }
#pragma unroll
    for (int r = 1; r < 4; ++r) {
        const int ad = arr[r - 1];
        v2h kr[8];
#pragma unroll
        for (int d = 0; d < 8; ++d) kr[d] = bpermh(ad, kh[d]);
        float a0 = 0.f, a1 = 0.f;
#pragma unroll
        for (int d = 0; d < 4; ++d) {
            a0 = fdot2(qh[d], kr[d], a0);
            a1 = fdot2(qh[4 + d], kr[4 + d], a1);
        }
        p0[r] = a0; p1[r] = a1;
    }
    {   // softmax, no max-subtract (|score*scale| <~ 20 << exp2 range)
        const float C = 0.51006974841f;   // (1/sqrt(8)) * log2(e)
        float s0 = 0.f, s1 = 0.f;
#pragma unroll
        for (int j = 0; j < 4; ++j) {
            p0[j] = __builtin_amdgcn_exp2f(p0[j] * C); s0 += p0[j];
            p1[j] = __builtin_amdgcn_exp2f(p1[j] * C); s1 += p1[j];
        }
        const float r0 = __builtin_amdgcn_rcpf(s0);
        const float r1 = __builtin_amdgcn_rcpf(s1);
#pragma unroll
        for (int j = 0; j < 4; ++j) { p0[j] *= r0; p1[j] *= r1; }
    }

    // ---- PV (f32): o_t = sum_r p[r] * v_{(t+r)%4}
    v2f o[8];
#pragma unroll
    for (int d = 0; d < 4; ++d) {
        o[d]     = splat2(p0[0]) * v[d];
        o[4 + d] = splat2(p1[0]) * v[4 + d];
    }
#pragma unroll
    for (int r = 1; r < 4; ++r) {
        const int ad = arr[r - 1];
        const v2f ps0 = splat2(p0[r]), ps1 = splat2(p1[r]);
#pragma unroll
        for (int d = 0; d < 8; ++d) {
            const v2f vr = bperm2(ad, v[d]);
            if (d < 4) o[d] = fma2(ps0, vr, o[d]);
            else       o[d] = fma2(ps1, vr, o[d]);
        }
    }

    // o -> half2 pairs for the h-loop dots
    v2h oh[8];
#pragma unroll
    for (int i = 0; i < 8; ++i) oh[i] = pkh(o[i].x, o[i].y);

    // ---- fused: h_t[c] = relu(o_t . W1T[c] + b1[c]) via fdot2;
    //      pooled_c = quadsum/4; lane accumulates its 8 output columns.
    const uint32_t* w1t = wsu + 384;
    const float* b1 = reinterpret_cast<const float*>(wsu) + 640;
    const int t8 = t * 8;
    const float4 ob0 = *reinterpret_cast<const float4*>(fco_b + t8);
    const float4 ob1 = *reinterpret_cast<const float4*>(fco_b + t8 + 4);
    v2f oacc[4];
    oacc[0].x = ob0.x; oacc[0].y = ob0.y; oacc[1].x = ob0.z; oacc[1].y = ob0.w;
    oacc[2].x = ob1.x; oacc[2].y = ob1.y; oacc[3].x = ob1.z; oacc[3].y = ob1.w;
    const float* fwt = fco_w + t8;   // lane-varying base

#pragma unroll 4
    for (int c = 0; c < 32; ++c) {
        const uint32_t* wr = w1t + c * 8;          // uniform -> s_load
        float a = b1[c];
#pragma unroll
        for (int p = 0; p < 8; ++p) a = fdot2(oh[p], ldh2(wr + p), a);
        const float h = fmaxf(a, 0.f);
        float s = h + bperm(ax1, h);
        s = s + bperm(ax2, s);
        const float pc = s * 0.25f;
        const v2f ps = splat2(pc);
        // lane-varying columns of fco_w: 4KB table, L1-resident
        const float4 f0 = *reinterpret_cast<const float4*>(fwt + c * 32);
        const float4 f1 = *reinterpret_cast<const float4*>(fwt + c * 32 + 4);
        v2f w01; w01.x = f0.x; w01.y = f0.y;
        v2f w23; w23.x = f0.z; w23.y = f0.w;
        v2f w45; w45.x = f1.x; w45.y = f1.y;
        v2f w67; w67.x = f1.z; w67.y = f1.w;
        oacc[0] = fma2(ps, w01, oacc[0]);
        oacc[1] = fma2(ps, w23, oacc[1]);
        oacc[2] = fma2(ps, w45, oacc[2]);
        oacc[3] = fma2(ps, w67, oacc[3]);
    }

    // ---- store: 16B/lane, contiguous across the quad and wave
    float* op = out + (size_t)f * 32 + t8;
    *reinterpret_cast<float4*>(op)     = make_float4(oacc[0].x, oacc[0].y, oacc[1].x, oacc[1].y);
    *reinterpret_cast<float4*>(op + 4) = make_float4(oacc[2].x, oacc[2].y, oacc[3].x, oacc[3].y);
}

extern "C" void kernel_launch(void* const* d_in, const int* in_sizes, int n_in,
                              void* d_out, int out_size, void* d_ws, size_t ws_size,
                              hipStream_t stream) {
    const float* node  = (const float*)d_in[0];
    const int*   fids  = (const int*)  d_in[1];
    const float* w_in  = (const float*)d_in[2];
    const float* b_in  = (const float*)d_in[3];
    const float* w_out = (const float*)d_in[4];
    const float* b_out = (const float*)d_in[5];
    const float* fc_w  = (const float*)d_in[6];
    const float* fc_b  = (const float*)d_in[7];
    const float* fco_w = (const float*)d_in[8];
    const float* fco_b = (const float*)d_in[9];
    float* out = (float*)d_out;
    uint32_t* wsu = (uint32_t*)d_ws;
    const int F = in_sizes[1] / 4;

    hipLaunchKernelGGL(fold_w, dim3(1), dim3(672), 0, stream,
                       w_in, w_out, b_out, fc_w, fc_b, wsu);
    const int threads = F * 4;
    const int blocks = (threads + 255) / 256;
    hipLaunchKernelGGL(face_net, dim3(blocks), dim3(256), 0, stream,
                       node, fids, b_in, wsu, fco_w, fco_b, out, F);
}